// Round 19
// baseline (43.225 us; speedup 1.0000x reference)
//
#include <hip/hip_runtime.h>
#include <math.h>

#define IH 512
#define IW 512
#define NPX (IH*IW)

// column-D + dpp-shift-box geometry, 2-row strips
#define TW 60                // output columns per tile (64 lanes -> D cols -2..61)
#define BH 8                 // tile height (4 waves x 2 rows)
#define NXT 9                // ceil(512/60)
#define YROWS 22             // image rows -7..14
#define YCOLS 74             // image cols -7..66
#define YSZ2 (YROWS*YCOLS)   // 1628 floats = 6512 B (only LDS)

// mono-fallback geometry (round-5 kernel)
#define TS 32
#define YHALO 7
#define RHALO 5
#define YD (TS + 2*YHALO)
#define RD (TS + 2*RHALO)
#define RSZ (RD*RD)
#define MYSZ (YD*YD)

#define FSQRT(x) __builtin_amdgcn_sqrtf(x)
#if __has_builtin(__builtin_amdgcn_exp2f)
#define FEXP2(x) __builtin_amdgcn_exp2f(x)
#else
#define FEXP2(x) exp2f(x)
#endif

// DPP wave_shl:1 (ctrl 0x130): lane i <- lane i+1, whole-wave, lane63 <- 0.
__device__ __forceinline__ float dpp_shl1(float x) {
    return __int_as_float(__builtin_amdgcn_update_dpp(
        0, __float_as_int(x), 0x130, 0xf, 0xf, true));
}

// ---------------- pre-pass: pack RGB to float4 + global Y plane --------------
// r18 post-mortem: duration tracks ISSUE COUNT (VALUBusy*dur == floor in every
// config); cut issue on the proven r15 base. Pack kernel: 1 dwordx4 load in
// the k-loop replaces 3 planar loads + 6 addr ops (-12% issue), and Y staging
// becomes a pure copy (Y was recomputed ~3.4x across overlapping halos).
__global__ __launch_bounds__(256)
void nlm_pack(const float* __restrict__ rgb,
              float4* __restrict__ pack,
              float* __restrict__ Yg) {
    int px = blockIdx.x * 256 + threadIdx.x;
    float r = rgb[px];
    float g = rgb[NPX + px];
    float b = rgb[2*NPX + px];
    pack[px] = make_float4(r, g, b, 0.f);
    Yg[px]   = 0.299f*r + 0.587f*g + 0.114f*b;
}

// ---------------- column-D compute kernel: dx-group per blockIdx.z -----------
// r15 structure exactly (NSLICE=4, BH=8, no clamp), with packed-RGB loads.
__global__ __launch_bounds__(256)
void nlm_part(const float4* __restrict__ pack,
              const float* __restrict__ Yg,
              const float* __restrict__ sigma,
              float4* __restrict__ ws) {
    __shared__ float YL[YSZ2];

    const int tid   = threadIdx.x;
    const int lane  = tid & 63;
    const int wavei = tid >> 6;
    const int tx0 = blockIdx.x * TW;
    const int ty0 = blockIdx.y * BH;
    const int slice = blockIdx.z;

    // stage luminance (pure copy from Yg): rows -7..14, cols -7..66 (circular)
    for (int idx = tid; idx < YSZ2; idx += 256) {
        int a = idx / YCOLS, b = idx - a*YCOLS;
        int gy = (ty0 + a - 7) & (IH-1);
        int gx = (tx0 + b - 7) & (IW-1);
        YL[idx] = Yg[gy*IW + gx];
    }
    __syncthreads();

    const float m2 = -1.4426950408889634f /
                     (fmaxf(sigma[0]*2.0f, 0.0f) + 1e-6f);

    const int l  = lane;         // D col cd = l-2; output col = l (<60)
    const int r0 = wavei*2;      // strip start row (0,2,4,6)

    // minuend Y at D col cd=l-2: image rows r0-2..r0+3 (storage r0+5+i)
    float yb6[6];
    #pragma unroll
    for (int i = 0; i < 6; ++i)
        yb6[i] = YL[(r0+5+i)*YCOLS + (l+5)];

    float accR[2]={0,0}, accG[2]={0,0}, accB[2]={0,0}, den[2]={0,0};

    // 4-slice dx decomposition (slices 0-2: 3 dx, slice 3: 2 dx)
    const int dxlo  = (slice < 3) ? (-5 + 3*slice) : 4;
    const int dxcnt = (slice < 3) ? 3 : 2;

    for (int u = 0; u < dxcnt; ++u) {
        const int dx = dxlo + u;
        const int ysb  = r0*YCOLS + (l + 5 - dx);     // Y subtrahend col base
        const int coli = (tx0 + l - dx) & (IW-1);     // rgb column (circular)

        // rolling Y subtrahend ring (6 slots): slot j = storage row r0+j at k=0
        float sub6[6];
        #pragma unroll
        for (int j = 0; j < 6; ++j)
            sub6[j] = YL[ysb + j*YCOLS];

        // packed-RGB 2-slot window; slot q&1 holds image row r0+q-5
        float4 rw[2];
        int oP = (((ty0 + r0 - 5) & (IH-1)) << 9) + coli;
        rw[0] = pack[oP];
        oP = (oP + IW) & (NPX-1);                     // -> row r0-4 (q=1)

        #pragma unroll
        for (int k = 0; k <= 10; ++k) {               // dy = 5 - k
            // load window slot q=k+1 (image row r0+k-4): one dwordx4
            rw[(k+1)&1] = pack[oP];
            oP = (oP + IW) & (NPX-1);
            if (k > 0)
                sub6[(k+5)%6] = YL[ysb + (k+5)*YCOLS]; // storage row r0+k+5

            // own-column E + vertical box via prefix (square folded into fma)
            float pre[7]; pre[0] = 0.f;
            #pragma unroll
            for (int i = 0; i < 6; ++i) {
                float d = yb6[i] - sub6[(i+k)%6];
                pre[i+1] = fmaf(d, d, pre[i]);
            }
            float V[2];
            V[0] = pre[5] - pre[0];
            V[1] = pre[6] - pre[1];

            // horizontal 5-col box over lanes l..l+4 via chained dpp shifts
            float box[2];
            #pragma unroll
            for (int rr = 0; rr < 2; ++rr) {
                float s1 = dpp_shl1(V[rr]);           // V[l+1]
                float s2 = dpp_shl1(s1);              // V[l+2]
                float s3 = dpp_shl1(s2);              // V[l+3]
                float s4 = dpp_shl1(s3);              // V[l+4]
                box[rr] = ((V[rr] + s1) + (s2 + s3)) + s4;
            }
            #pragma unroll
            for (int rr = 0; rr < 2; ++rr) {
                float w = FEXP2(FSQRT(fmaxf(box[rr], 0.f)) * m2);
                float4 p = rw[(k+rr)&1];
                accR[rr] = fmaf(w, p.x, accR[rr]);
                accG[rr] = fmaf(w, p.y, accG[rr]);
                accB[rr] = fmaf(w, p.z, accB[rr]);
                den[rr] += w;
            }
        }
    }

    if (l < TW && tx0 + l < IW) {
        #pragma unroll
        for (int rr = 0; rr < 2; ++rr) {
            int px = (ty0 + r0 + rr)*IW + tx0 + l;
            ws[(size_t)slice*NPX + px] =
                make_float4(accR[rr], accG[rr], accB[rr], den[rr]);
        }
    }
}

// ---------------- combine: sum 4 slices, normalize, clip ---------------------
__global__ __launch_bounds__(256)
void nlm_combine(const float4* __restrict__ ws, float* __restrict__ out) {
    int px = blockIdx.x * 256 + threadIdx.x;
    float4 a = ws[px];
    float4 b = ws[NPX + px];
    float4 c = ws[2*(size_t)NPX + px];
    float4 d = ws[3*(size_t)NPX + px];
    float r  = (a.x + b.x) + (c.x + d.x);
    float g  = (a.y + b.y) + (c.y + d.y);
    float bl = (a.z + b.z) + (c.z + d.z);
    float w  = (a.w + b.w) + (c.w + d.w);
    float iw = 1.0f / w;
    out[px]           = fminf(fmaxf(r  * iw, 0.f), 1.f);
    out[NPX + px]     = fminf(fmaxf(g  * iw, 0.f), 1.f);
    out[2*NPX + px]   = fminf(fmaxf(bl * iw, 0.f), 1.f);
}

// ---------------- fallback: round-5 monolithic kernel (ws too small) ---------
__global__ __launch_bounds__(256)
void nlm_mono(const float* __restrict__ rgb,
              const float* __restrict__ sigma,
              float* __restrict__ out) {
    __shared__ float Y[MYSZ];
    __shared__ float RGBL[3 * RSZ];

    const int tid = threadIdx.x;
    const int tx0 = blockIdx.x * TS;
    const int ty0 = blockIdx.y * TS;

    const float* Rp = rgb;
    const float* Gp = rgb + NPX;
    const float* Bp = rgb + 2 * NPX;

    for (int idx = tid; idx < MYSZ; idx += 256) {
        int a = idx / YD, b = idx - a * YD;
        int gy = (ty0 + a - YHALO) & (IH - 1);
        int gx = (tx0 + b - YHALO) & (IW - 1);
        int g = gy * IW + gx;
        Y[idx] = 0.299f * Rp[g] + 0.587f * Gp[g] + 0.114f * Bp[g];
    }
    for (int idx = tid; idx < RSZ; idx += 256) {
        int a = idx / RD, b = idx - a * RD;
        int gy = (ty0 + a - RHALO) & (IH - 1);
        int gx = (tx0 + b - RHALO) & (IW - 1);
        int g = gy * IW + gx;
        RGBL[idx]           = Rp[g];
        RGBL[RSZ + idx]     = Gp[g];
        RGBL[2 * RSZ + idx] = Bp[g];
    }
    __syncthreads();

    const float minv_h = -1.0f / (fmaxf(sigma[0] * 2.0f, 0.0f) + 1e-6f);
    const int tx = tid & 31;
    const int tz = tid >> 5;
    const int r0 = tz * 4;

    const int ybase = (YHALO + r0 - 2) * YD + (YHALO + tx - 2);
    float yb[8][5];
    #pragma unroll
    for (int i = 0; i < 8; ++i)
        #pragma unroll
        for (int b = 0; b < 5; ++b)
            yb[i][b] = Y[ybase + i * YD + b];

    float accR[4] = {0.f,0.f,0.f,0.f}, accG[4] = {0.f,0.f,0.f,0.f};
    float accB[4] = {0.f,0.f,0.f,0.f}, den[4] = {0.f,0.f,0.f,0.f};

    for (int dx = -5; dx <= 5; ++dx) {
        const int ybd = (YHALO + r0 - 7) * YD + (YHALO + tx - 2 - dx);
        const int rbd = (RHALO + r0 - 5) * RD + (RHALO + tx - dx);

        #pragma unroll
        for (int k = 0; k <= 10; ++k) {
            float hs[8];
            #pragma unroll
            for (int i = 0; i < 8; ++i) {
                float s = 0.f;
                #pragma unroll
                for (int b = 0; b < 5; ++b) {
                    float d = yb[i][b] - Y[ybd + (i + k) * YD + b];
                    s = fmaf(d, d, s);
                }
                hs[i] = s;
            }
            float pre[9];
            pre[0] = 0.f;
            #pragma unroll
            for (int i = 0; i < 8; ++i) pre[i + 1] = pre[i] + hs[i];
            #pragma unroll
            for (int rr = 0; rr < 4; ++rr) {
                float box = pre[rr + 5] - pre[rr];
                float w = __expf(FSQRT(box) * minv_h);
                const int s2 = rbd + (rr + k) * RD;
                accR[rr] = fmaf(w, RGBL[s2], accR[rr]);
                accG[rr] = fmaf(w, RGBL[RSZ + s2], accG[rr]);
                accB[rr] = fmaf(w, RGBL[2 * RSZ + s2], accB[rr]);
                den[rr] += w;
            }
        }
    }

    #pragma unroll
    for (int rr = 0; rr < 4; ++rr) {
        int px = (ty0 + r0 + rr) * IW + tx0 + tx;
        float iw = 1.0f / den[rr];
        out[px]           = fminf(fmaxf(accR[rr] * iw, 0.f), 1.f);
        out[NPX + px]     = fminf(fmaxf(accG[rr] * iw, 0.f), 1.f);
        out[2 * NPX + px] = fminf(fmaxf(accB[rr] * iw, 0.f), 1.f);
    }
}

extern "C" void kernel_launch(void* const* d_in, const int* in_sizes, int n_in,
                              void* d_out, int out_size, void* d_ws, size_t ws_size,
                              hipStream_t stream) {
    const float* rgb   = (const float*)d_in[0];
    const float* sigma = (const float*)d_in[1];
    float* out = (float*)d_out;

    // ws layout: [4 x NPX float4 slices | NPX float4 pack | NPX float Y]
    const size_t need = (size_t)5 * NPX * sizeof(float4) + (size_t)NPX * sizeof(float);
    if (ws_size >= need) {
        float4* ws   = (float4*)d_ws;
        float4* pack = ws + (size_t)4 * NPX;
        float*  Yg   = (float*)(ws + (size_t)5 * NPX);
        nlm_pack<<<dim3(NPX / 256), dim3(256), 0, stream>>>(rgb, pack, Yg);
        dim3 grid(NXT, IH / BH, 4);        // 9 x 64 x 4 = 2304 blocks
        nlm_part<<<grid, dim3(256), 0, stream>>>(pack, Yg, sigma, ws);
        nlm_combine<<<dim3(NPX / 256), dim3(256), 0, stream>>>(ws, out);
    } else {
        dim3 grid(IW / TS, IH / TS);
        nlm_mono<<<grid, dim3(256), 0, stream>>>(rgb, sigma, out);
    }
}

// Round 20
// 40.801 us; speedup vs baseline: 1.0594x; 1.0594x over previous
//
#include <hip/hip_runtime.h>
#include <math.h>

#define IH 512
#define IW 512
#define NPX (IH*IW)

// column-D + dpp-shift-box geometry, 2-row strips, 8-wave blocks
#define TW 60                // output columns per tile (64 lanes -> D cols -2..61)
#define BH 16                // tile height (8 waves x 2 rows)
#define NXT 9                // ceil(512/60)
#define YROWS 30             // image rows -7..22
#define YCOLS 74             // image cols -7..66
#define YSZ2 (YROWS*YCOLS)   // 2220 floats = 8880 B (only LDS)

// mono-fallback geometry (round-5 kernel)
#define TS 32
#define YHALO 7
#define RHALO 5
#define YD (TS + 2*YHALO)
#define RD (TS + 2*RHALO)
#define RSZ (RD*RD)
#define MYSZ (YD*YD)

#define FSQRT(x) __builtin_amdgcn_sqrtf(x)
#if __has_builtin(__builtin_amdgcn_exp2f)
#define FEXP2(x) __builtin_amdgcn_exp2f(x)
#else
#define FEXP2(x) exp2f(x)
#endif

// DPP wave_shl:1 (ctrl 0x130): lane i <- lane i+1, whole-wave, lane63 <- 0.
__device__ __forceinline__ float dpp_shl1(float x) {
    return __int_as_float(__builtin_amdgcn_update_dpp(
        0, __float_as_int(x), 0x130, 0xf, 0xf, true));
}

// ---------------- column-D compute kernel: dx-group per blockIdx.z -----------
// r19 post-mortem: the un-attacked cost is STAGING+BARRIER per block
// generation (~2-4k cyc each; r15 = 9 generations/CU ~ 8-11us of 30; r16's
// +50% blocks cost +3.7us = the staging delta). This round amortizes it:
// 512-thread blocks (8 waves x 2-row strips, per-wave code identical to r15)
// and NSLICE=2 -> 576 blocks (2.25 gen/CU), staged elements 3.75M -> 1.28M,
// per-wave compute 2x (5.5 dx avg). VGPR/wave unchanged.
__global__ __launch_bounds__(512)
void nlm_part(const float* __restrict__ rgb,
              const float* __restrict__ sigma,
              float4* __restrict__ ws) {
    __shared__ float YL[YSZ2];

    const int tid   = threadIdx.x;
    const int lane  = tid & 63;
    const int wavei = tid >> 6;          // 0..7
    const int tx0 = blockIdx.x * TW;
    const int ty0 = blockIdx.y * BH;
    const int slice = blockIdx.z;        // 0: dx -5..0, 1: dx 1..5

    const float* Rp = rgb;
    const float* Gp = rgb + NPX;
    const float* Bp = rgb + 2*NPX;

    // stage luminance: rows -7..22, cols -7..66 (circular)
    for (int idx = tid; idx < YSZ2; idx += 512) {
        int a = idx / YCOLS, b = idx - a*YCOLS;
        int gy = (ty0 + a - 7) & (IH-1);
        int gx = (tx0 + b - 7) & (IW-1);
        int g = gy*IW + gx;
        YL[idx] = 0.299f*Rp[g] + 0.587f*Gp[g] + 0.114f*Bp[g];
    }
    __syncthreads();

    const float m2 = -1.4426950408889634f /
                     (fmaxf(sigma[0]*2.0f, 0.0f) + 1e-6f);

    const int l  = lane;         // D col cd = l-2; output col = l (<60)
    const int r0 = wavei*2;      // strip start row (0,2,...,14)

    // minuend Y at D col cd=l-2: image rows r0-2..r0+3 (storage r0+5+i)
    float yb6[6];
    #pragma unroll
    for (int i = 0; i < 6; ++i)
        yb6[i] = YL[(r0+5+i)*YCOLS + (l+5)];

    float accR[2]={0,0}, accG[2]={0,0}, accB[2]={0,0}, den[2]={0,0};

    const int dxlo  = slice ? 1 : -5;
    const int dxcnt = slice ? 5 : 6;

    for (int u = 0; u < dxcnt; ++u) {
        const int dx = dxlo + u;
        const int ysb  = r0*YCOLS + (l + 5 - dx);     // Y subtrahend col base
        const int coli = (tx0 + l - dx) & (IW-1);     // rgb column (circular)

        // rolling Y subtrahend ring (6 slots): slot j = storage row r0+j at k=0
        float sub6[6];
        #pragma unroll
        for (int j = 0; j < 6; ++j)
            sub6[j] = YL[ysb + j*YCOLS];

        // RGB 2-slot window; slot q&1 holds image row r0+q-5
        float rw[2], gw[2], bw[2];
        int oP = (((ty0 + r0 - 5) & (IH-1)) << 9) + coli;
        rw[0] = Rp[oP]; gw[0] = Gp[oP]; bw[0] = Bp[oP];
        oP = (oP + IW) & (NPX-1);                     // -> row r0-4 (q=1)

        #pragma unroll
        for (int k = 0; k <= 10; ++k) {               // dy = 5 - k
            // load window slot q=k+1 (image row r0+k-4)
            rw[(k+1)&1] = Rp[oP];
            gw[(k+1)&1] = Gp[oP];
            bw[(k+1)&1] = Bp[oP];
            oP = (oP + IW) & (NPX-1);
            if (k > 0)
                sub6[(k+5)%6] = YL[ysb + (k+5)*YCOLS]; // storage row r0+k+5

            // own-column E + vertical box via prefix (square folded into fma)
            float pre[7]; pre[0] = 0.f;
            #pragma unroll
            for (int i = 0; i < 6; ++i) {
                float d = yb6[i] - sub6[(i+k)%6];
                pre[i+1] = fmaf(d, d, pre[i]);
            }
            float V[2];
            V[0] = pre[5] - pre[0];
            V[1] = pre[6] - pre[1];

            // horizontal 5-col box over lanes l..l+4 via chained dpp shifts
            float box[2];
            #pragma unroll
            for (int rr = 0; rr < 2; ++rr) {
                float s1 = dpp_shl1(V[rr]);           // V[l+1]
                float s2 = dpp_shl1(s1);              // V[l+2]
                float s3 = dpp_shl1(s2);              // V[l+3]
                float s4 = dpp_shl1(s3);              // V[l+4]
                box[rr] = ((V[rr] + s1) + (s2 + s3)) + s4;
            }
            #pragma unroll
            for (int rr = 0; rr < 2; ++rr) {
                float w = FEXP2(FSQRT(fmaxf(box[rr], 0.f)) * m2);
                accR[rr] = fmaf(w, rw[(k+rr)&1], accR[rr]);
                accG[rr] = fmaf(w, gw[(k+rr)&1], accG[rr]);
                accB[rr] = fmaf(w, bw[(k+rr)&1], accB[rr]);
                den[rr] += w;
            }
        }
    }

    if (l < TW && tx0 + l < IW) {
        #pragma unroll
        for (int rr = 0; rr < 2; ++rr) {
            int px = (ty0 + r0 + rr)*IW + tx0 + l;
            ws[(size_t)slice*NPX + px] =
                make_float4(accR[rr], accG[rr], accB[rr], den[rr]);
        }
    }
}

// ---------------- combine: sum 2 slices, normalize, clip ---------------------
__global__ __launch_bounds__(256)
void nlm_combine(const float4* __restrict__ ws, float* __restrict__ out) {
    int px = blockIdx.x * 256 + threadIdx.x;
    float4 a = ws[px];
    float4 b = ws[NPX + px];
    float r  = a.x + b.x;
    float g  = a.y + b.y;
    float bl = a.z + b.z;
    float w  = a.w + b.w;
    float iw = 1.0f / w;
    out[px]           = fminf(fmaxf(r  * iw, 0.f), 1.f);
    out[NPX + px]     = fminf(fmaxf(g  * iw, 0.f), 1.f);
    out[2*NPX + px]   = fminf(fmaxf(bl * iw, 0.f), 1.f);
}

// ---------------- fallback: round-5 monolithic kernel (ws too small) ---------
__global__ __launch_bounds__(256)
void nlm_mono(const float* __restrict__ rgb,
              const float* __restrict__ sigma,
              float* __restrict__ out) {
    __shared__ float Y[MYSZ];
    __shared__ float RGBL[3 * RSZ];

    const int tid = threadIdx.x;
    const int tx0 = blockIdx.x * TS;
    const int ty0 = blockIdx.y * TS;

    const float* Rp = rgb;
    const float* Gp = rgb + NPX;
    const float* Bp = rgb + 2 * NPX;

    for (int idx = tid; idx < MYSZ; idx += 256) {
        int a = idx / YD, b = idx - a * YD;
        int gy = (ty0 + a - YHALO) & (IH - 1);
        int gx = (tx0 + b - YHALO) & (IW - 1);
        int g = gy * IW + gx;
        Y[idx] = 0.299f * Rp[g] + 0.587f * Gp[g] + 0.114f * Bp[g];
    }
    for (int idx = tid; idx < RSZ; idx += 256) {
        int a = idx / RD, b = idx - a * RD;
        int gy = (ty0 + a - RHALO) & (IH - 1);
        int gx = (tx0 + b - RHALO) & (IW - 1);
        int g = gy * IW + gx;
        RGBL[idx]           = Rp[g];
        RGBL[RSZ + idx]     = Gp[g];
        RGBL[2 * RSZ + idx] = Bp[g];
    }
    __syncthreads();

    const float minv_h = -1.0f / (fmaxf(sigma[0] * 2.0f, 0.0f) + 1e-6f);
    const int tx = tid & 31;
    const int tz = tid >> 5;
    const int r0 = tz * 4;

    const int ybase = (YHALO + r0 - 2) * YD + (YHALO + tx - 2);
    float yb[8][5];
    #pragma unroll
    for (int i = 0; i < 8; ++i)
        #pragma unroll
        for (int b = 0; b < 5; ++b)
            yb[i][b] = Y[ybase + i * YD + b];

    float accR[4] = {0.f,0.f,0.f,0.f}, accG[4] = {0.f,0.f,0.f,0.f};
    float accB[4] = {0.f,0.f,0.f,0.f}, den[4] = {0.f,0.f,0.f,0.f};

    for (int dx = -5; dx <= 5; ++dx) {
        const int ybd = (YHALO + r0 - 7) * YD + (YHALO + tx - 2 - dx);
        const int rbd = (RHALO + r0 - 5) * RD + (RHALO + tx - dx);

        #pragma unroll
        for (int k = 0; k <= 10; ++k) {
            float hs[8];
            #pragma unroll
            for (int i = 0; i < 8; ++i) {
                float s = 0.f;
                #pragma unroll
                for (int b = 0; b < 5; ++b) {
                    float d = yb[i][b] - Y[ybd + (i + k) * YD + b];
                    s = fmaf(d, d, s);
                }
                hs[i] = s;
            }
            float pre[9];
            pre[0] = 0.f;
            #pragma unroll
            for (int i = 0; i < 8; ++i) pre[i + 1] = pre[i] + hs[i];
            #pragma unroll
            for (int rr = 0; rr < 4; ++rr) {
                float box = pre[rr + 5] - pre[rr];
                float w = __expf(FSQRT(box) * minv_h);
                const int s2 = rbd + (rr + k) * RD;
                accR[rr] = fmaf(w, RGBL[s2], accR[rr]);
                accG[rr] = fmaf(w, RGBL[RSZ + s2], accG[rr]);
                accB[rr] = fmaf(w, RGBL[2 * RSZ + s2], accB[rr]);
                den[rr] += w;
            }
        }
    }

    #pragma unroll
    for (int rr = 0; rr < 4; ++rr) {
        int px = (ty0 + r0 + rr) * IW + tx0 + tx;
        float iw = 1.0f / den[rr];
        out[px]           = fminf(fmaxf(accR[rr] * iw, 0.f), 1.f);
        out[NPX + px]     = fminf(fmaxf(accG[rr] * iw, 0.f), 1.f);
        out[2 * NPX + px] = fminf(fmaxf(accB[rr] * iw, 0.f), 1.f);
    }
}

extern "C" void kernel_launch(void* const* d_in, const int* in_sizes, int n_in,
                              void* d_out, int out_size, void* d_ws, size_t ws_size,
                              hipStream_t stream) {
    const float* rgb   = (const float*)d_in[0];
    const float* sigma = (const float*)d_in[1];
    float* out = (float*)d_out;

    const size_t need = (size_t)2 * NPX * sizeof(float4);
    if (ws_size >= need) {
        float4* ws = (float4*)d_ws;
        dim3 grid(NXT, IH / BH, 2);        // 9 x 32 x 2 = 576 blocks
        nlm_part<<<grid, dim3(512), 0, stream>>>(rgb, sigma, ws);
        nlm_combine<<<dim3(NPX / 256), dim3(256), 0, stream>>>(ws, out);
    } else {
        dim3 grid(IW / TS, IH / TS);
        nlm_mono<<<grid, dim3(256), 0, stream>>>(rgb, sigma, out);
    }
}

// Round 21
// 35.620 us; speedup vs baseline: 1.2135x; 1.1455x over previous
//
#include <hip/hip_runtime.h>
#include <math.h>

#define IH 512
#define IW 512
#define NPX (IH*IW)

// column-D + dpp-shift-box geometry, 2-row strips  (r15 structure, NSLICE=3)
#define TW 60                // output columns per tile (64 lanes -> D cols -2..61)
#define BH 8                 // tile height (4 waves x 2 rows)
#define NXT 9                // ceil(512/60)
#define YROWS 22             // image rows -7..14
#define YCOLS 74             // image cols -7..66
#define YSZ2 (YROWS*YCOLS)   // 1628 floats = 6512 B (only LDS)

// mono-fallback geometry (round-5 kernel)
#define TS 32
#define YHALO 7
#define RHALO 5
#define YD (TS + 2*YHALO)
#define RD (TS + 2*RHALO)
#define RSZ (RD*RD)
#define MYSZ (YD*YD)

#define FSQRT(x) __builtin_amdgcn_sqrtf(x)
#if __has_builtin(__builtin_amdgcn_exp2f)
#define FEXP2(x) __builtin_amdgcn_exp2f(x)
#else
#define FEXP2(x) exp2f(x)
#endif

// DPP wave_shl:1 (ctrl 0x130): lane i <- lane i+1, whole-wave, lane63 <- 0.
__device__ __forceinline__ float dpp_shl1(float x) {
    return __int_as_float(__builtin_amdgcn_update_dpp(
        0, __float_as_int(x), 0x130, 0xf, 0xf, true));
}

// ---------------- column-D compute kernel: dx-group per blockIdx.z -----------
// Ledger r9-r20: r15 (BH=8, 256thr, 4 slices) = 36.0us best; occupancy/ILP/
// issue-cut/staging levers all individually falsified; slice-count curve at
// 256-thr blocks: 6sl=39.7, 4sl=36.0. This round: 3 slices (-25% staging
// generations, -25% combine traffic, per-wave k-loop code identical to r15).
__global__ __launch_bounds__(256)
void nlm_part(const float* __restrict__ rgb,
              const float* __restrict__ sigma,
              float4* __restrict__ ws) {
    __shared__ float YL[YSZ2];

    const int tid   = threadIdx.x;
    const int lane  = tid & 63;
    const int wavei = tid >> 6;
    const int tx0 = blockIdx.x * TW;
    const int ty0 = blockIdx.y * BH;
    const int slice = blockIdx.z;        // 0: dx -5..-2, 1: -1..2, 2: 3..5

    const float* Rp = rgb;
    const float* Gp = rgb + NPX;
    const float* Bp = rgb + 2*NPX;

    // stage luminance: rows -7..14, cols -7..66 (circular)
    for (int idx = tid; idx < YSZ2; idx += 256) {
        int a = idx / YCOLS, b = idx - a*YCOLS;
        int gy = (ty0 + a - 7) & (IH-1);
        int gx = (tx0 + b - 7) & (IW-1);
        int g = gy*IW + gx;
        YL[idx] = 0.299f*Rp[g] + 0.587f*Gp[g] + 0.114f*Bp[g];
    }
    __syncthreads();

    const float m2 = -1.4426950408889634f /
                     (fmaxf(sigma[0]*2.0f, 0.0f) + 1e-6f);

    const int l  = lane;         // D col cd = l-2; output col = l (<60)
    const int r0 = wavei*2;      // strip start row (0,2,4,6)

    // minuend Y at D col cd=l-2: image rows r0-2..r0+3 (storage r0+5+i)
    float yb6[6];
    #pragma unroll
    for (int i = 0; i < 6; ++i)
        yb6[i] = YL[(r0+5+i)*YCOLS + (l+5)];

    float accR[2]={0,0}, accG[2]={0,0}, accB[2]={0,0}, den[2]={0,0};

    // 3-slice dx decomposition: {-5..-2}, {-1..2}, {3..5}
    const int dxlo  = (slice == 0) ? -5 : (slice == 1 ? -1 : 3);
    const int dxcnt = (slice == 2) ? 3 : 4;

    for (int u = 0; u < dxcnt; ++u) {
        const int dx = dxlo + u;
        const int ysb  = r0*YCOLS + (l + 5 - dx);     // Y subtrahend col base
        const int coli = (tx0 + l - dx) & (IW-1);     // rgb column (circular)

        // rolling Y subtrahend ring (6 slots): slot j = storage row r0+j at k=0
        float sub6[6];
        #pragma unroll
        for (int j = 0; j < 6; ++j)
            sub6[j] = YL[ysb + j*YCOLS];

        // RGB 2-slot window; slot q&1 holds image row r0+q-5
        float rw[2], gw[2], bw[2];
        int oP = (((ty0 + r0 - 5) & (IH-1)) << 9) + coli;
        rw[0] = Rp[oP]; gw[0] = Gp[oP]; bw[0] = Bp[oP];
        oP = (oP + IW) & (NPX-1);                     // -> row r0-4 (q=1)

        #pragma unroll
        for (int k = 0; k <= 10; ++k) {               // dy = 5 - k
            // load window slot q=k+1 (image row r0+k-4)
            rw[(k+1)&1] = Rp[oP];
            gw[(k+1)&1] = Gp[oP];
            bw[(k+1)&1] = Bp[oP];
            oP = (oP + IW) & (NPX-1);
            if (k > 0)
                sub6[(k+5)%6] = YL[ysb + (k+5)*YCOLS]; // storage row r0+k+5

            // own-column E + vertical box via prefix (square folded into fma)
            float pre[7]; pre[0] = 0.f;
            #pragma unroll
            for (int i = 0; i < 6; ++i) {
                float d = yb6[i] - sub6[(i+k)%6];
                pre[i+1] = fmaf(d, d, pre[i]);
            }
            float V[2];
            V[0] = pre[5] - pre[0];
            V[1] = pre[6] - pre[1];

            // horizontal 5-col box over lanes l..l+4 via chained dpp shifts
            float box[2];
            #pragma unroll
            for (int rr = 0; rr < 2; ++rr) {
                float s1 = dpp_shl1(V[rr]);           // V[l+1]
                float s2 = dpp_shl1(s1);              // V[l+2]
                float s3 = dpp_shl1(s2);              // V[l+3]
                float s4 = dpp_shl1(s3);              // V[l+4]
                box[rr] = ((V[rr] + s1) + (s2 + s3)) + s4;
            }
            #pragma unroll
            for (int rr = 0; rr < 2; ++rr) {
                float w = FEXP2(FSQRT(fmaxf(box[rr], 0.f)) * m2);
                accR[rr] = fmaf(w, rw[(k+rr)&1], accR[rr]);
                accG[rr] = fmaf(w, gw[(k+rr)&1], accG[rr]);
                accB[rr] = fmaf(w, bw[(k+rr)&1], accB[rr]);
                den[rr] += w;
            }
        }
    }

    if (l < TW && tx0 + l < IW) {
        #pragma unroll
        for (int rr = 0; rr < 2; ++rr) {
            int px = (ty0 + r0 + rr)*IW + tx0 + l;
            ws[(size_t)slice*NPX + px] =
                make_float4(accR[rr], accG[rr], accB[rr], den[rr]);
        }
    }
}

// ---------------- combine: sum 3 slices, normalize, clip ---------------------
__global__ __launch_bounds__(256)
void nlm_combine(const float4* __restrict__ ws, float* __restrict__ out) {
    int px = blockIdx.x * 256 + threadIdx.x;
    float4 a = ws[px];
    float4 b = ws[NPX + px];
    float4 c = ws[2*(size_t)NPX + px];
    float r  = (a.x + b.x) + c.x;
    float g  = (a.y + b.y) + c.y;
    float bl = (a.z + b.z) + c.z;
    float w  = (a.w + b.w) + c.w;
    float iw = 1.0f / w;
    out[px]           = fminf(fmaxf(r  * iw, 0.f), 1.f);
    out[NPX + px]     = fminf(fmaxf(g  * iw, 0.f), 1.f);
    out[2*NPX + px]   = fminf(fmaxf(bl * iw, 0.f), 1.f);
}

// ---------------- fallback: round-5 monolithic kernel (ws too small) ---------
__global__ __launch_bounds__(256)
void nlm_mono(const float* __restrict__ rgb,
              const float* __restrict__ sigma,
              float* __restrict__ out) {
    __shared__ float Y[MYSZ];
    __shared__ float RGBL[3 * RSZ];

    const int tid = threadIdx.x;
    const int tx0 = blockIdx.x * TS;
    const int ty0 = blockIdx.y * TS;

    const float* Rp = rgb;
    const float* Gp = rgb + NPX;
    const float* Bp = rgb + 2 * NPX;

    for (int idx = tid; idx < MYSZ; idx += 256) {
        int a = idx / YD, b = idx - a * YD;
        int gy = (ty0 + a - YHALO) & (IH - 1);
        int gx = (tx0 + b - YHALO) & (IW - 1);
        int g = gy * IW + gx;
        Y[idx] = 0.299f * Rp[g] + 0.587f * Gp[g] + 0.114f * Bp[g];
    }
    for (int idx = tid; idx < RSZ; idx += 256) {
        int a = idx / RD, b = idx - a * RD;
        int gy = (ty0 + a - RHALO) & (IH - 1);
        int gx = (tx0 + b - RHALO) & (IW - 1);
        int g = gy * IW + gx;
        RGBL[idx]           = Rp[g];
        RGBL[RSZ + idx]     = Gp[g];
        RGBL[2 * RSZ + idx] = Bp[g];
    }
    __syncthreads();

    const float minv_h = -1.0f / (fmaxf(sigma[0] * 2.0f, 0.0f) + 1e-6f);
    const int tx = tid & 31;
    const int tz = tid >> 5;
    const int r0 = tz * 4;

    const int ybase = (YHALO + r0 - 2) * YD + (YHALO + tx - 2);
    float yb[8][5];
    #pragma unroll
    for (int i = 0; i < 8; ++i)
        #pragma unroll
        for (int b = 0; b < 5; ++b)
            yb[i][b] = Y[ybase + i * YD + b];

    float accR[4] = {0.f,0.f,0.f,0.f}, accG[4] = {0.f,0.f,0.f,0.f};
    float accB[4] = {0.f,0.f,0.f,0.f}, den[4] = {0.f,0.f,0.f,0.f};

    for (int dx = -5; dx <= 5; ++dx) {
        const int ybd = (YHALO + r0 - 7) * YD + (YHALO + tx - 2 - dx);
        const int rbd = (RHALO + r0 - 5) * RD + (RHALO + tx - dx);

        #pragma unroll
        for (int k = 0; k <= 10; ++k) {
            float hs[8];
            #pragma unroll
            for (int i = 0; i < 8; ++i) {
                float s = 0.f;
                #pragma unroll
                for (int b = 0; b < 5; ++b) {
                    float d = yb[i][b] - Y[ybd + (i + k) * YD + b];
                    s = fmaf(d, d, s);
                }
                hs[i] = s;
            }
            float pre[9];
            pre[0] = 0.f;
            #pragma unroll
            for (int i = 0; i < 8; ++i) pre[i + 1] = pre[i] + hs[i];
            #pragma unroll
            for (int rr = 0; rr < 4; ++rr) {
                float box = pre[rr + 5] - pre[rr];
                float w = __expf(FSQRT(box) * minv_h);
                const int s2 = rbd + (rr + k) * RD;
                accR[rr] = fmaf(w, RGBL[s2], accR[rr]);
                accG[rr] = fmaf(w, RGBL[RSZ + s2], accG[rr]);
                accB[rr] = fmaf(w, RGBL[2 * RSZ + s2], accB[rr]);
                den[rr] += w;
            }
        }
    }

    #pragma unroll
    for (int rr = 0; rr < 4; ++rr) {
        int px = (ty0 + r0 + rr) * IW + tx0 + tx;
        float iw = 1.0f / den[rr];
        out[px]           = fminf(fmaxf(accR[rr] * iw, 0.f), 1.f);
        out[NPX + px]     = fminf(fmaxf(accG[rr] * iw, 0.f), 1.f);
        out[2 * NPX + px] = fminf(fmaxf(accB[rr] * iw, 0.f), 1.f);
    }
}

extern "C" void kernel_launch(void* const* d_in, const int* in_sizes, int n_in,
                              void* d_out, int out_size, void* d_ws, size_t ws_size,
                              hipStream_t stream) {
    const float* rgb   = (const float*)d_in[0];
    const float* sigma = (const float*)d_in[1];
    float* out = (float*)d_out;

    const size_t need = (size_t)3 * NPX * sizeof(float4);
    if (ws_size >= need) {
        float4* ws = (float4*)d_ws;
        dim3 grid(NXT, IH / BH, 3);        // 9 x 64 x 3 = 1728 blocks
        nlm_part<<<grid, dim3(256), 0, stream>>>(rgb, sigma, ws);
        nlm_combine<<<dim3(NPX / 256), dim3(256), 0, stream>>>(ws, out);
    } else {
        dim3 grid(IW / TS, IH / TS);
        nlm_mono<<<grid, dim3(256), 0, stream>>>(rgb, sigma, out);
    }
}